// Round 5
// baseline (335.724 us; speedup 1.0000x reference)
//
#include <hip/hip_runtime.h>

#define N_NODES  100000
#define M_PAD    100096   // 782 * 128 (and 1564 * 64)
#define N_EDGES  1600000
#define N_GRAPHS 512
#define IN_DIM   128
#define HID_DIM  256
#define OUT_DIM  128

#define NB       782      // buckets of 128 nodes
#define BCAP     3072     // mean 2048, +22 sigma headroom
#define CHUNK    2048     // edges per bucket_v2 block
#define BKB      ((N_EDGES + CHUNK - 1) / CHUNK)   // 782

typedef __bf16 bf16x8 __attribute__((ext_vector_type(8)));
typedef __bf16 bf16x4 __attribute__((ext_vector_type(4)));
typedef __bf16 bf16x2 __attribute__((ext_vector_type(2)));
typedef float  f32x4  __attribute__((ext_vector_type(4)));

// ---- packed weight buffer layout (frag-ordered, LINEAR group stream) ----
// 32 groups x 8 frags x 512 elems: L1 groups 0-7, L2 8-23, L3 24-31.
#define WP_L2_BASE 32768
#define WP_L3_BASE 98304
#define WP_TOTAL   131072

// ---------------- fused init ----------------
#define R_X    (N_NODES * IN_DIM / 4)
#define R_APAD ((M_PAD - N_NODES) * IN_DIM / 4)
#define R_WP   WP_TOTAL
#define R_OUT  (N_GRAPHS * OUT_DIM / 4)
#define R_CUR  NB
#define R_TOTAL (R_X + R_APAD + R_WP + R_OUT + R_CUR)

__global__ __launch_bounds__(256) void init_kernel(const float* __restrict__ x,
                                                   const float* __restrict__ W1,
                                                   const float* __restrict__ W2,
                                                   const float* __restrict__ Wo,
                                                   __bf16* __restrict__ xb,
                                                   __bf16* __restrict__ Apad,
                                                   __bf16* __restrict__ Wp,
                                                   float* __restrict__ outbuf,
                                                   int* __restrict__ gcursor) {
    long long i = (long long)blockIdx.x * blockDim.x + threadIdx.x;
    if (i < R_X) {
        float4 v = ((const float4*)x)[i];
        bf16x4 h;
        h.x = (__bf16)v.x; h.y = (__bf16)v.y; h.z = (__bf16)v.z; h.w = (__bf16)v.w;
        ((bf16x4*)xb)[i] = h;
        return;
    }
    i -= R_X;
    if (i < R_APAD) {
        bf16x4 z; z.x = (__bf16)0.f; z.y = (__bf16)0.f; z.z = (__bf16)0.f; z.w = (__bf16)0.f;
        ((bf16x4*)Apad)[i] = z;
        return;
    }
    i -= R_APAD;
    if (i < R_WP) {
        int idx = (int)i;
        const float* src;
        int K, Nn, base;
        if (idx < WP_L2_BASE)      { src = W1; K = 128; Nn = 256; base = 0; }
        else if (idx < WP_L3_BASE) { src = W2; K = 256; Nn = 256; base = WP_L2_BASE; }
        else                       { src = Wo; K = 256; Nn = 128; base = WP_L3_BASE; }
        int r0 = idx - base;
        int slabElems = 32 * K;          // power of two
        int j = r0 / slabElems;
        int r = r0 % slabElems;
        int KS = K / 32;
        int p = r >> 9;
        int lane = (r >> 3) & 63;
        int e = r & 7;
        int s = p % KS, t = p / KS;
        int quad = lane >> 4, l16 = lane & 15;
        int n = j * 32 + t * 16 + l16;
        int k = s * 32 + quad * 8 + e;
        Wp[idx] = (__bf16)src[(size_t)k * Nn + n];
        return;
    }
    i -= R_WP;
    if (i < R_OUT) {
        ((float4*)outbuf)[i] = make_float4(0.f, 0.f, 0.f, 0.f);
        return;
    }
    i -= R_OUT;
    if (i < R_CUR) gcursor[i] = 0;
}

// ---------------- bucket_v2: LDS-staged edge binning ----------------
__global__ __launch_bounds__(256) void bucket_v2_kernel(const int* __restrict__ ei,
                                                        int* __restrict__ gcursor,
                                                        unsigned* __restrict__ pairBuf) {
    __shared__ int lcnt[NB];
    __shared__ int lbase[NB];
    const int tid = threadIdx.x;
    const int e0 = blockIdx.x * CHUNK;

    for (int b = tid; b < NB; b += 256) lcnt[b] = 0;
    __syncthreads();

    for (int i = tid; i < CHUNK; i += 256) {
        int e = e0 + i;
        if (e < N_EDGES) atomicAdd(&lcnt[ei[N_EDGES + e] >> 7], 1);
    }
    __syncthreads();

    for (int b = tid; b < NB; b += 256) {
        int c = lcnt[b];
        lbase[b] = c ? atomicAdd(&gcursor[b], c) : 0;
        lcnt[b] = 0;
    }
    __syncthreads();

    for (int i = tid; i < CHUNK; i += 256) {
        int e = e0 + i;
        if (e < N_EDGES) {
            int s = ei[e];
            int d = ei[N_EDGES + e];
            int b = d >> 7;
            int pos = lbase[b] + atomicAdd(&lcnt[b], 1);
            if (pos < BCAP)
                pairBuf[(size_t)b * BCAP + pos] = (unsigned)s | ((unsigned)(d & 127) << 17);
        }
    }
}

// ---------------- passB: per-bucket CSR build (bucket-strided) ----------------
__global__ __launch_bounds__(256) void passB_kernel(const unsigned* __restrict__ pairBuf,
                                                    const int* __restrict__ gcursor,
                                                    int* __restrict__ nbr,
                                                    int* __restrict__ offsets,
                                                    int* __restrict__ deg) {
    __shared__ int lcnt[128];
    __shared__ int loffs[128];
    __shared__ int lcur[128];
    const int b = blockIdx.x;
    const int tid = threadIdx.x;
    const int node0 = b << 7;
    const int cnt = min(gcursor[b], BCAP);
    const int base = b * BCAP;
    const unsigned* pb = pairBuf + (size_t)b * BCAP;

    if (tid < 128) { lcnt[tid] = 0; lcur[tid] = 0; }
    __syncthreads();

    for (int i = tid; i < cnt; i += 256)
        atomicAdd(&lcnt[pb[i] >> 17], 1);
    __syncthreads();

    if (tid < 128) loffs[tid] = lcnt[tid];
    __syncthreads();
    for (int st = 1; st < 128; st <<= 1) {
        int add = (tid < 128 && tid >= st) ? loffs[tid - st] : 0;
        __syncthreads();
        if (tid < 128) loffs[tid] += add;
        __syncthreads();
    }
    int excl = 0;
    if (tid < 128) {
        excl = loffs[tid] - lcnt[tid];
        int node = node0 + tid;
        if (node < N_NODES) {
            deg[node] = lcnt[tid];
            offsets[node] = base + excl;
        }
    }
    __syncthreads();
    if (tid < 128) loffs[tid] = excl;
    __syncthreads();

    for (int i = tid; i < cnt; i += 256) {
        unsigned u = pb[i];
        int dl = u >> 17;
        int slot = atomicAdd(&lcur[dl], 1);
        nbr[base + loffs[dl] + slot] = (int)(u & 0x1FFFF);
    }
}

// ---------------- gather aggregate (at memory floor) ----------------
__global__ __launch_bounds__(256) void aggregate_kernel(const __bf16* __restrict__ xb,
                                                        const int* __restrict__ offsets,
                                                        const int* __restrict__ deg,
                                                        const int* __restrict__ nbr,
                                                        __bf16* __restrict__ A) {
    int v = blockIdx.x * 4 + (threadIdx.x >> 6);
    v = __builtin_amdgcn_readfirstlane(v);
    int lane = threadIdx.x & 63;
    if (v >= N_NODES) return;
    int off = offsets[v];
    int len = deg[v];
    const int c0 = lane * 2;
    bf16x2 self = *(const bf16x2*)(xb + (size_t)v * IN_DIM + c0);
    float ax = (float)self.x, ay = (float)self.y;

    int addr = off + lane;
    if (addr > NB * BCAP - 1) addr = NB * BCAP - 1;
    int myidx = nbr[addr];

    int lim = len < 64 ? len : 64;
    int j = 0;
    for (; j + 8 <= lim; j += 8) {
        int s0 = __shfl(myidx, j + 0, 64);
        int s1 = __shfl(myidx, j + 1, 64);
        int s2 = __shfl(myidx, j + 2, 64);
        int s3 = __shfl(myidx, j + 3, 64);
        int s4 = __shfl(myidx, j + 4, 64);
        int s5 = __shfl(myidx, j + 5, 64);
        int s6 = __shfl(myidx, j + 6, 64);
        int s7 = __shfl(myidx, j + 7, 64);
        bf16x2 v0 = *(const bf16x2*)(xb + (size_t)s0 * IN_DIM + c0);
        bf16x2 v1 = *(const bf16x2*)(xb + (size_t)s1 * IN_DIM + c0);
        bf16x2 v2 = *(const bf16x2*)(xb + (size_t)s2 * IN_DIM + c0);
        bf16x2 v3 = *(const bf16x2*)(xb + (size_t)s3 * IN_DIM + c0);
        bf16x2 v4 = *(const bf16x2*)(xb + (size_t)s4 * IN_DIM + c0);
        bf16x2 v5 = *(const bf16x2*)(xb + (size_t)s5 * IN_DIM + c0);
        bf16x2 v6 = *(const bf16x2*)(xb + (size_t)s6 * IN_DIM + c0);
        bf16x2 v7 = *(const bf16x2*)(xb + (size_t)s7 * IN_DIM + c0);
        ax += (float)v0.x + (float)v1.x + (float)v2.x + (float)v3.x
            + (float)v4.x + (float)v5.x + (float)v6.x + (float)v7.x;
        ay += (float)v0.y + (float)v1.y + (float)v2.y + (float)v3.y
            + (float)v4.y + (float)v5.y + (float)v6.y + (float)v7.y;
    }
    for (; j < lim; ++j) {
        int s = __shfl(myidx, j, 64);
        bf16x2 vv = *(const bf16x2*)(xb + (size_t)s * IN_DIM + c0);
        ax += (float)vv.x;
        ay += (float)vv.y;
    }
    for (; j < len; ++j) {
        int s = nbr[off + j];
        bf16x2 vv = *(const bf16x2*)(xb + (size_t)s * IN_DIM + c0);
        ax += (float)vv.x;
        ay += (float)vv.y;
    }
    bf16x2 h;
    h.x = (__bf16)ax;
    h.y = (__bf16)ay;
    *(bf16x2*)(A + (size_t)v * IN_DIM + c0) = h;
}

// ---------------- fused 3-layer MLP + pool ----------------
// v6: v5 (DMA weight staging) + DEPTH-2 prefetch + COUNTED vmcnt(4).
// v5 post-mortem: its vmcnt(0) waited for the DMA issued at the TOP of the
// SAME body (~300cy cover vs ~500+cy DMA latency) -> exposed stall every
// body = the drain-0 anti-pattern (m218: counted-vs-drain0 is +38-73%).
// v6: 4 LDS buffers, group g lives in WB[g&3]. Body g:
//   [issue stage(g+2)] [ds_read WB[g&3]] [MFMA] [store]
//   [s_waitcnt vmcnt(4)]  <- waits only stage(g+1), issued a FULL body ago;
//                            stage(g+2)'s 4 DMAs stay in flight
//   [raw s_barrier]
// Buffer safety: WB[(g+2)&3] last read in body g-2; per-body barrier bounds
// wave skew to 1 body. vm-op stream is pure (4 DMA/body/wave; biases in LDS,
// A-frags only at prologue / LDS layer transitions), so the count is exact.
// LDS: H 32KB + WB 32KB + LB 2.5KB -> 2 blocks/CU.
#define MLP_WAVES   2
#define MLP_ROWS_W  32
#define MLP_ROWS_B  (MLP_WAVES * MLP_ROWS_W)   // 64

#define GLOAD_LDS16(gp, lp)                                              \
    __builtin_amdgcn_global_load_lds(                                    \
        (const __attribute__((address_space(1))) void*)(gp),             \
        (__attribute__((address_space(3))) void*)(lp), 16, 0, 0)

// stage half a group (4 KB) per wave: 4 x 1KB DMA; dest linear, src lane*16B
__device__ __forceinline__ void stage_dma(const __bf16* __restrict__ g,
                                          __bf16* __restrict__ l, int wid, int lane) {
    #pragma unroll
    for (int c = 0; c < 4; ++c)
        GLOAD_LDS16(g + wid * 2048 + c * 512 + lane * 8, l + wid * 2048 + c * 512);
}

__device__ __forceinline__ void read_frags(const __bf16* __restrict__ lb, int lane,
                                           bf16x8* __restrict__ f) {
    #pragma unroll
    for (int e = 0; e < 8; ++e)
        f[e] = *(const bf16x8*)(lb + (e * 64 + lane) * 8);
}

__device__ __forceinline__ void store_H(__bf16* __restrict__ H, int j, int quad, int l16,
                                        const f32x4 (&acc)[2][2], float bt0, float bt1) {
    const int c7 = l16 & 7;
    const int ch = l16 >> 3;
    #pragma unroll
    for (int i = 0; i < 2; ++i)
        #pragma unroll
        for (int t = 0; t < 2; ++t) {
            const float bb = t ? bt1 : bt0;
            #pragma unroll
            for (int rr = 0; rr < 4; ++rr) {
                int row = i * 16 + quad * 4 + rr;
                int cidx = (j * 4 + t * 2 + ch + row) & 31;
                float v = fmaxf(acc[i][t][rr] + bb, 0.f);
                H[row * 256 + cidx * 8 + c7] = (__bf16)v;
            }
        }
}

// counted wait: leave the 4 DMAs of stage(g+2) in flight, require stage(g+1)
// (issued one full body earlier) to have landed. Then raw barrier.
#define BODY_BOT()  do {                                   \
    asm volatile("s_waitcnt vmcnt(4)" ::: "memory");       \
    __builtin_amdgcn_sched_barrier(0);                     \
    __builtin_amdgcn_s_barrier();                          \
} while (0)

__global__ __launch_bounds__(128, 2) void mlp_fused(const __bf16* __restrict__ A,
                                                    const __bf16* __restrict__ Wp,
                                                    const float* __restrict__ b1,
                                                    const float* __restrict__ b2,
                                                    const float* __restrict__ bo,
                                                    float* __restrict__ out,
                                                    const int* __restrict__ batch) {
    __shared__ __align__(16) __bf16 H[MLP_WAVES][32 * 256];   // 32 KB
    __shared__ __align__(16) __bf16 WB[4][4096];              // 32 KB, 4-deep ring
    __shared__ float LB[640];                                 // 2.5 KB biases

    const int tid  = threadIdx.x;
    const int wid  = tid >> 6;
    const int lane = tid & 63;
    const int quad = lane >> 4, l16 = lane & 15;
    __bf16* Hw = H[wid];

    const size_t mblk = (size_t)blockIdx.x * MLP_ROWS_B + wid * MLP_ROWS_W;
    const int r0g = (int)mblk;
    int gfirst = (r0g < N_NODES) ? batch[r0g] : -2;
    int glast  = (r0g + 31 < N_NODES) ? batch[r0g + 31] : -1;

    bf16x8 a[2][8];
    bf16x8 f[8];

    // ---- prologue: stage groups 0,1; biases -> LDS; layer-1 A-frags ----
    stage_dma(Wp, WB[0], wid, lane);
    stage_dma(Wp + 4096, WB[1], wid, lane);
    for (int t = tid; t < 640; t += 128) {
        float v = (t < 256) ? b1[t] : (t < 512) ? b2[t - 256] : bo[t - 512];
        LB[t] = v;
    }
    #pragma unroll
    for (int i = 0; i < 2; ++i)
        #pragma unroll
        for (int s = 0; s < 4; ++s)
            a[i][s] = *(const bf16x8*)(A + (mblk + i * 16 + l16) * IN_DIM + s * 32 + quad * 8);
    __syncthreads();   // one-time full drain: stages 0,1 + biases + A-frags

    // ---- layer 1: bodies g = 0..7 (group g = one 32-col slab, KS=4) ----
    #pragma unroll 1
    for (int g = 0; g < 8; ++g) {
        stage_dma(Wp + (size_t)(g + 2) * 4096, WB[(g + 2) & 3], wid, lane);
        read_frags(WB[g & 3], lane, f);
        float bt0 = LB[g * 32 + l16];
        float bt1 = LB[g * 32 + 16 + l16];
        f32x4 acc[2][2] = {};
        #pragma unroll
        for (int p = 0; p < 8; ++p) {
            const int t = p >> 2, s = p & 3;
            acc[0][t] = __builtin_amdgcn_mfma_f32_16x16x32_bf16(a[0][s], f[p], acc[0][t], 0, 0, 0);
            acc[1][t] = __builtin_amdgcn_mfma_f32_16x16x32_bf16(a[1][s], f[p], acc[1][t], 0, 0, 0);
        }
        store_H(Hw, g, quad, l16, acc, bt0, bt1);
        BODY_BOT();
    }

    // ---- layer 2 A-frags from LDS (wave-private H) ----
    #pragma unroll
    for (int i = 0; i < 2; ++i)
        #pragma unroll
        for (int s = 0; s < 8; ++s) {
            int row = i * 16 + l16;
            a[i][s] = *(const bf16x8*)(Hw + row * 256 + (((s * 4 + quad) + row) & 31) * 8);
        }

    // ---- layer 2: bodies g = 8..23 (slab j: even g -> acc t0, odd g -> t1) ----
    #pragma unroll 1
    for (int j = 0; j < 8; ++j) {
        const int g = 8 + 2 * j;
        f32x4 acc[2][2] = {};
        // even body
        stage_dma(Wp + (size_t)(g + 2) * 4096, WB[(g + 2) & 3], wid, lane);
        read_frags(WB[g & 3], lane, f);
        #pragma unroll
        for (int p = 0; p < 8; ++p) {
            acc[0][0] = __builtin_amdgcn_mfma_f32_16x16x32_bf16(a[0][p], f[p], acc[0][0], 0, 0, 0);
            acc[1][0] = __builtin_amdgcn_mfma_f32_16x16x32_bf16(a[1][p], f[p], acc[1][0], 0, 0, 0);
        }
        BODY_BOT();
        // odd body
        stage_dma(Wp + (size_t)(g + 3) * 4096, WB[(g + 3) & 3], wid, lane);
        read_frags(WB[(g + 1) & 3], lane, f);
        #pragma unroll
        for (int p = 0; p < 8; ++p) {
            acc[0][1] = __builtin_amdgcn_mfma_f32_16x16x32_bf16(a[0][p], f[p], acc[0][1], 0, 0, 0);
            acc[1][1] = __builtin_amdgcn_mfma_f32_16x16x32_bf16(a[1][p], f[p], acc[1][1], 0, 0, 0);
        }
        float bt0 = LB[256 + j * 32 + l16];
        float bt1 = LB[256 + j * 32 + 16 + l16];
        store_H(Hw, j, quad, l16, acc, bt0, bt1);
        BODY_BOT();
    }

    // ---- layer 3 A-frags from LDS ----
    #pragma unroll
    for (int i = 0; i < 2; ++i)
        #pragma unroll
        for (int s = 0; s < 8; ++s) {
            int row = i * 16 + l16;
            a[i][s] = *(const bf16x8*)(Hw + row * 256 + (((s * 4 + quad) + row) & 31) * 8);
        }

    // ---- layer 3: bodies g = 24..31 (slab j), pooled atomic output ----
    // (stages for g+2 > 31 read past Wp into pairBuf — harmless, keeps the
    //  vmcnt count uniform)
    #pragma unroll 1
    for (int j = 0; j < 4; ++j) {
        const int g = 24 + 2 * j;
        f32x4 acc[2][2] = {};
        // even body
        stage_dma(Wp + (size_t)(g + 2) * 4096, WB[(g + 2) & 3], wid, lane);
        read_frags(WB[g & 3], lane, f);
        #pragma unroll
        for (int p = 0; p < 8; ++p) {
            acc[0][0] = __builtin_amdgcn_mfma_f32_16x16x32_bf16(a[0][p], f[p], acc[0][0], 0, 0, 0);
            acc[1][0] = __builtin_amdgcn_mfma_f32_16x16x32_bf16(a[1][p], f[p], acc[1][0], 0, 0, 0);
        }
        BODY_BOT();
        // odd body
        stage_dma(Wp + (size_t)(g + 3) * 4096, WB[(g + 3) & 3], wid, lane);
        read_frags(WB[(g + 1) & 3], lane, f);
        #pragma unroll
        for (int p = 0; p < 8; ++p) {
            acc[0][1] = __builtin_amdgcn_mfma_f32_16x16x32_bf16(a[0][p], f[p], acc[0][1], 0, 0, 0);
            acc[1][1] = __builtin_amdgcn_mfma_f32_16x16x32_bf16(a[1][p], f[p], acc[1][1], 0, 0, 0);
        }
        float bt0 = LB[512 + j * 32 + l16];
        float bt1 = LB[512 + j * 32 + 16 + l16];

        if (gfirst == glast) {
            #pragma unroll
            for (int t = 0; t < 2; ++t) {
                float sum = 0.f;
                #pragma unroll
                for (int i = 0; i < 2; ++i)
                    #pragma unroll
                    for (int rr = 0; rr < 4; ++rr) sum += acc[i][t][rr];
                sum += __shfl_xor(sum, 16, 64);
                sum += __shfl_xor(sum, 32, 64);
                if (quad == 0) {
                    int c = j * 32 + t * 16 + l16;
                    float bb = t ? bt1 : bt0;
                    atomicAdd(out + (size_t)gfirst * OUT_DIM + c, sum + 32.f * bb);
                }
            }
        } else {
            #pragma unroll
            for (int i = 0; i < 2; ++i)
                #pragma unroll
                for (int rr = 0; rr < 4; ++rr) {
                    int m = r0g + i * 16 + quad * 4 + rr;
                    if (m < N_NODES) {
                        int g2 = batch[m];
                        #pragma unroll
                        for (int t = 0; t < 2; ++t) {
                            int c = j * 32 + t * 16 + l16;
                            float bb = t ? bt1 : bt0;
                            atomicAdd(out + (size_t)g2 * OUT_DIM + c, acc[i][t][rr] + bb);
                        }
                    }
                }
        }
        BODY_BOT();
    }
}

extern "C" void kernel_launch(void* const* d_in, const int* in_sizes, int n_in,
                              void* d_out, int out_size, void* d_ws, size_t ws_size,
                              hipStream_t stream) {
    const float* x  = (const float*)d_in[0];
    const int*   ei = (const int*)d_in[1];
    const int*   bi = (const int*)d_in[2];
    const float* W1 = (const float*)d_in[3];
    const float* b1 = (const float*)d_in[4];
    const float* W2 = (const float*)d_in[5];
    const float* b2 = (const float*)d_in[6];
    const float* Wo = (const float*)d_in[7];
    const float* bo = (const float*)d_in[8];
    float* out = (float*)d_out;

    __bf16* A  = (__bf16*)d_ws;                        // [M_PAD][128]
    __bf16* xb = A + (size_t)M_PAD * IN_DIM;           // [N_NODES][128]
    __bf16* Wp = xb + (size_t)N_NODES * IN_DIM;        // [131072] packed frag-ordered
    unsigned* pairBuf = (unsigned*)(Wp + WP_TOTAL);    // [NB*BCAP]
    int* nbr      = (int*)(pairBuf + (size_t)NB * BCAP);
    int* offsets  = nbr + (size_t)NB * BCAP;
    int* deg      = offsets + N_NODES;
    int* gcursor  = deg + N_NODES;

    // ---- fused init ----
    init_kernel<<<(R_TOTAL + 255) / 256, 256, 0, stream>>>(
        x, W1, W2, Wo, xb, A + (size_t)N_NODES * IN_DIM, Wp, out, gcursor);

    // ---- CSR build ----
    bucket_v2_kernel<<<BKB, 256, 0, stream>>>(ei, gcursor, pairBuf);
    passB_kernel<<<NB, 256, 0, stream>>>(pairBuf, gcursor, nbr, offsets, deg);

    // ---- aggregate ----
    aggregate_kernel<<<(N_NODES + 3) / 4, 256, 0, stream>>>(xb, offsets, deg, nbr, A);

    // ---- fused MLP + pool (2-wave blocks, depth-2 DMA ring, counted vmcnt) ----
    mlp_fused<<<M_PAD / MLP_ROWS_B, MLP_WAVES * 64, 0, stream>>>(A, Wp, b1, b2, bo, out, bi);
}

// Round 6
// 332.445 us; speedup vs baseline: 1.0099x; 1.0099x over previous
//
#include <hip/hip_runtime.h>

#define N_NODES  100000
#define M_PAD    100096   // 782 * 128 (and 1564 * 64)
#define N_EDGES  1600000
#define N_GRAPHS 512
#define IN_DIM   128
#define HID_DIM  256
#define OUT_DIM  128

#define NB       782      // buckets of 128 nodes
#define BCAP     3072     // mean 2048, +22 sigma headroom
#define CHUNK    2048     // edges per bucket_v2 block
#define BKB      ((N_EDGES + CHUNK - 1) / CHUNK)   // 782

typedef __bf16 bf16x8 __attribute__((ext_vector_type(8)));
typedef __bf16 bf16x4 __attribute__((ext_vector_type(4)));
typedef __bf16 bf16x2 __attribute__((ext_vector_type(2)));
typedef float  f32x4  __attribute__((ext_vector_type(4)));

// ---- packed weight buffer layout (frag-ordered, LINEAR group stream) ----
// 32 groups x 8 frags x 512 elems: L1 groups 0-7, L2 8-23, L3 24-31.
#define WP_L2_BASE 32768
#define WP_L3_BASE 98304
#define WP_TOTAL   131072

// ---------------- fused init ----------------
#define R_X    (N_NODES * IN_DIM / 4)
#define R_APAD ((M_PAD - N_NODES) * IN_DIM / 4)
#define R_WP   WP_TOTAL
#define R_OUT  (N_GRAPHS * OUT_DIM / 4)
#define R_CUR  NB
#define R_TOTAL (R_X + R_APAD + R_WP + R_OUT + R_CUR)

__global__ __launch_bounds__(256) void init_kernel(const float* __restrict__ x,
                                                   const float* __restrict__ W1,
                                                   const float* __restrict__ W2,
                                                   const float* __restrict__ Wo,
                                                   __bf16* __restrict__ xb,
                                                   __bf16* __restrict__ Apad,
                                                   __bf16* __restrict__ Wp,
                                                   float* __restrict__ outbuf,
                                                   int* __restrict__ gcursor) {
    long long i = (long long)blockIdx.x * blockDim.x + threadIdx.x;
    if (i < R_X) {
        float4 v = ((const float4*)x)[i];
        bf16x4 h;
        h.x = (__bf16)v.x; h.y = (__bf16)v.y; h.z = (__bf16)v.z; h.w = (__bf16)v.w;
        ((bf16x4*)xb)[i] = h;
        return;
    }
    i -= R_X;
    if (i < R_APAD) {
        bf16x4 z; z.x = (__bf16)0.f; z.y = (__bf16)0.f; z.z = (__bf16)0.f; z.w = (__bf16)0.f;
        ((bf16x4*)Apad)[i] = z;
        return;
    }
    i -= R_APAD;
    if (i < R_WP) {
        int idx = (int)i;
        const float* src;
        int K, Nn, base;
        if (idx < WP_L2_BASE)      { src = W1; K = 128; Nn = 256; base = 0; }
        else if (idx < WP_L3_BASE) { src = W2; K = 256; Nn = 256; base = WP_L2_BASE; }
        else                       { src = Wo; K = 256; Nn = 128; base = WP_L3_BASE; }
        int r0 = idx - base;
        int slabElems = 32 * K;          // power of two
        int j = r0 / slabElems;
        int r = r0 % slabElems;
        int KS = K / 32;
        int p = r >> 9;
        int lane = (r >> 3) & 63;
        int e = r & 7;
        int s = p % KS, t = p / KS;
        int quad = lane >> 4, l16 = lane & 15;
        int n = j * 32 + t * 16 + l16;
        int k = s * 32 + quad * 8 + e;
        Wp[idx] = (__bf16)src[(size_t)k * Nn + n];
        return;
    }
    i -= R_WP;
    if (i < R_OUT) {
        ((float4*)outbuf)[i] = make_float4(0.f, 0.f, 0.f, 0.f);
        return;
    }
    i -= R_OUT;
    if (i < R_CUR) gcursor[i] = 0;
}

// ---------------- bucket_v2: LDS-staged edge binning ----------------
__global__ __launch_bounds__(256) void bucket_v2_kernel(const int* __restrict__ ei,
                                                        int* __restrict__ gcursor,
                                                        unsigned* __restrict__ pairBuf) {
    __shared__ int lcnt[NB];
    __shared__ int lbase[NB];
    const int tid = threadIdx.x;
    const int e0 = blockIdx.x * CHUNK;

    for (int b = tid; b < NB; b += 256) lcnt[b] = 0;
    __syncthreads();

    for (int i = tid; i < CHUNK; i += 256) {
        int e = e0 + i;
        if (e < N_EDGES) atomicAdd(&lcnt[ei[N_EDGES + e] >> 7], 1);
    }
    __syncthreads();

    for (int b = tid; b < NB; b += 256) {
        int c = lcnt[b];
        lbase[b] = c ? atomicAdd(&gcursor[b], c) : 0;
        lcnt[b] = 0;
    }
    __syncthreads();

    for (int i = tid; i < CHUNK; i += 256) {
        int e = e0 + i;
        if (e < N_EDGES) {
            int s = ei[e];
            int d = ei[N_EDGES + e];
            int b = d >> 7;
            int pos = lbase[b] + atomicAdd(&lcnt[b], 1);
            if (pos < BCAP)
                pairBuf[(size_t)b * BCAP + pos] = (unsigned)s | ((unsigned)(d & 127) << 17);
        }
    }
}

// ---------------- passB: per-bucket CSR build (bucket-strided) ----------------
__global__ __launch_bounds__(256) void passB_kernel(const unsigned* __restrict__ pairBuf,
                                                    const int* __restrict__ gcursor,
                                                    int* __restrict__ nbr,
                                                    int* __restrict__ offsets,
                                                    int* __restrict__ deg) {
    __shared__ int lcnt[128];
    __shared__ int loffs[128];
    __shared__ int lcur[128];
    const int b = blockIdx.x;
    const int tid = threadIdx.x;
    const int node0 = b << 7;
    const int cnt = min(gcursor[b], BCAP);
    const int base = b * BCAP;
    const unsigned* pb = pairBuf + (size_t)b * BCAP;

    if (tid < 128) { lcnt[tid] = 0; lcur[tid] = 0; }
    __syncthreads();

    for (int i = tid; i < cnt; i += 256)
        atomicAdd(&lcnt[pb[i] >> 17], 1);
    __syncthreads();

    if (tid < 128) loffs[tid] = lcnt[tid];
    __syncthreads();
    for (int st = 1; st < 128; st <<= 1) {
        int add = (tid < 128 && tid >= st) ? loffs[tid - st] : 0;
        __syncthreads();
        if (tid < 128) loffs[tid] += add;
        __syncthreads();
    }
    int excl = 0;
    if (tid < 128) {
        excl = loffs[tid] - lcnt[tid];
        int node = node0 + tid;
        if (node < N_NODES) {
            deg[node] = lcnt[tid];
            offsets[node] = base + excl;
        }
    }
    __syncthreads();
    if (tid < 128) loffs[tid] = excl;
    __syncthreads();

    for (int i = tid; i < cnt; i += 256) {
        unsigned u = pb[i];
        int dl = u >> 17;
        int slot = atomicAdd(&lcur[dl], 1);
        nbr[base + loffs[dl] + slot] = (int)(u & 0x1FFFF);
    }
}

// ---------------- gather aggregate (at memory floor) ----------------
__global__ __launch_bounds__(256) void aggregate_kernel(const __bf16* __restrict__ xb,
                                                        const int* __restrict__ offsets,
                                                        const int* __restrict__ deg,
                                                        const int* __restrict__ nbr,
                                                        __bf16* __restrict__ A) {
    int v = blockIdx.x * 4 + (threadIdx.x >> 6);
    v = __builtin_amdgcn_readfirstlane(v);
    int lane = threadIdx.x & 63;
    if (v >= N_NODES) return;
    int off = offsets[v];
    int len = deg[v];
    const int c0 = lane * 2;
    bf16x2 self = *(const bf16x2*)(xb + (size_t)v * IN_DIM + c0);
    float ax = (float)self.x, ay = (float)self.y;

    int addr = off + lane;
    if (addr > NB * BCAP - 1) addr = NB * BCAP - 1;
    int myidx = nbr[addr];

    int lim = len < 64 ? len : 64;
    int j = 0;
    for (; j + 8 <= lim; j += 8) {
        int s0 = __shfl(myidx, j + 0, 64);
        int s1 = __shfl(myidx, j + 1, 64);
        int s2 = __shfl(myidx, j + 2, 64);
        int s3 = __shfl(myidx, j + 3, 64);
        int s4 = __shfl(myidx, j + 4, 64);
        int s5 = __shfl(myidx, j + 5, 64);
        int s6 = __shfl(myidx, j + 6, 64);
        int s7 = __shfl(myidx, j + 7, 64);
        bf16x2 v0 = *(const bf16x2*)(xb + (size_t)s0 * IN_DIM + c0);
        bf16x2 v1 = *(const bf16x2*)(xb + (size_t)s1 * IN_DIM + c0);
        bf16x2 v2 = *(const bf16x2*)(xb + (size_t)s2 * IN_DIM + c0);
        bf16x2 v3 = *(const bf16x2*)(xb + (size_t)s3 * IN_DIM + c0);
        bf16x2 v4 = *(const bf16x2*)(xb + (size_t)s4 * IN_DIM + c0);
        bf16x2 v5 = *(const bf16x2*)(xb + (size_t)s5 * IN_DIM + c0);
        bf16x2 v6 = *(const bf16x2*)(xb + (size_t)s6 * IN_DIM + c0);
        bf16x2 v7 = *(const bf16x2*)(xb + (size_t)s7 * IN_DIM + c0);
        ax += (float)v0.x + (float)v1.x + (float)v2.x + (float)v3.x
            + (float)v4.x + (float)v5.x + (float)v6.x + (float)v7.x;
        ay += (float)v0.y + (float)v1.y + (float)v2.y + (float)v3.y
            + (float)v4.y + (float)v5.y + (float)v6.y + (float)v7.y;
    }
    for (; j < lim; ++j) {
        int s = __shfl(myidx, j, 64);
        bf16x2 vv = *(const bf16x2*)(xb + (size_t)s * IN_DIM + c0);
        ax += (float)vv.x;
        ay += (float)vv.y;
    }
    for (; j < len; ++j) {
        int s = nbr[off + j];
        bf16x2 vv = *(const bf16x2*)(xb + (size_t)s * IN_DIM + c0);
        ax += (float)vv.x;
        ay += (float)vv.y;
    }
    bf16x2 h;
    h.x = (__bf16)ax;
    h.y = (__bf16)ay;
    *(bf16x2*)(A + (size_t)v * IN_DIM + c0) = h;
}

// ---------------- fused 3-layer MLP + pool ----------------
// v7: v2's proven barrier-free structure (1-wave blocks, wave-private reg
// weight dbuf, rolled loops) at 64 ROWS PER WAVE.
// Post-mortem of v3-v6: every block-level staging/sync scheme (LDS weights,
// multi-wave sharing, DMA + drain0, DMA + counted vmcnt) LOST to v2's 72us -
// 16 MFMA (~80cy) per 8KB group cannot hide ~250cy of L2 latency no matter
// where the wait sits. The lever is the RATIO: 64 rows -> 32 MFMA per group,
// same weight bytes. Weight L2 traffic halves (826->413MB); stall per row
// halves. H = 32KB/block (5 blocks/CU by LDS); a[4][8]=128 VGPR held per
// layer, launch_bounds(64,2) caps at 256.
#define MLP_ROWS_W  64

__device__ __forceinline__ void load_group_p(const __bf16* __restrict__ p, int lane,
                                             bf16x8* __restrict__ dst) {
    #pragma unroll
    for (int e = 0; e < 8; ++e)
        dst[e] = *(const bf16x8*)(p + (e * 64 + lane) * 8);
}

// 64-row H store with the standard row-XOR column swizzle (verified in v3)
__device__ __forceinline__ void store_H(__bf16* __restrict__ H, int j, int quad, int l16,
                                        const f32x4 (&acc)[4][2], float bt0, float bt1) {
    const int c7 = l16 & 7;
    const int ch = l16 >> 3;
    #pragma unroll
    for (int i = 0; i < 4; ++i)
        #pragma unroll
        for (int t = 0; t < 2; ++t) {
            const float bb = t ? bt1 : bt0;
            #pragma unroll
            for (int rr = 0; rr < 4; ++rr) {
                int row = i * 16 + quad * 4 + rr;
                int cidx = (j * 4 + t * 2 + ch + row) & 31;
                float v = fmaxf(acc[i][t][rr] + bb, 0.f);
                H[row * 256 + cidx * 8 + c7] = (__bf16)v;
            }
        }
}

__global__ __launch_bounds__(64, 2) void mlp_fused(const __bf16* __restrict__ A,
                                                   const __bf16* __restrict__ Wp,
                                                   const float* __restrict__ b1,
                                                   const float* __restrict__ b2,
                                                   const float* __restrict__ bo,
                                                   float* __restrict__ out,
                                                   const int* __restrict__ batch) {
    __shared__ __align__(16) __bf16 H[MLP_ROWS_W * 256];   // 32 KB

    const int lane = threadIdx.x;
    const int quad = lane >> 4, l16 = lane & 15;
    const size_t mblk = (size_t)blockIdx.x * MLP_ROWS_W;
    const int r0g = (int)mblk;
    int gfirst = (r0g < N_NODES) ? batch[r0g] : -2;
    int glast  = (r0g + 63 < N_NODES) ? batch[r0g + 63] : -1;

    bf16x8 a[4][8];
    bf16x8 buf0[8];
    bf16x8 buf1[8];

    const __bf16* wp = Wp;           // group pointer (advances through linear stream)
    load_group_p(wp, lane, buf0);    // prologue: group 0

    // layer-1 A-frags (K=128: slots 0..3)
    #pragma unroll
    for (int i = 0; i < 4; ++i)
        #pragma unroll
        for (int s = 0; s < 4; ++s)
            a[i][s] = *(const bf16x8*)(A + (mblk + i * 16 + l16) * IN_DIM + s * 32 + quad * 8);

    // ---- layer 1: groups 0..7 (unroll-by-2 for buffer parity) ----
    #pragma unroll 1
    for (int j = 0; j < 8; j += 2) {
        {   // even j: compute buf0, prefetch into buf1
            load_group_p(wp + 4096, lane, buf1);
            float bt0 = b1[j * 32 + l16];
            float bt1 = b1[j * 32 + 16 + l16];
            f32x4 acc[4][2] = {};
            #pragma unroll
            for (int p = 0; p < 8; ++p) {
                const int t = p >> 2, s = p & 3;
                #pragma unroll
                for (int i = 0; i < 4; ++i)
                    acc[i][t] = __builtin_amdgcn_mfma_f32_16x16x32_bf16(a[i][s], buf0[p], acc[i][t], 0, 0, 0);
            }
            store_H(H, j, quad, l16, acc, bt0, bt1);
        }
        {   // odd j+1: compute buf1, prefetch into buf0
            load_group_p(wp + 8192, lane, buf0);
            float bt0 = b1[(j + 1) * 32 + l16];
            float bt1 = b1[(j + 1) * 32 + 16 + l16];
            f32x4 acc[4][2] = {};
            #pragma unroll
            for (int p = 0; p < 8; ++p) {
                const int t = p >> 2, s = p & 3;
                #pragma unroll
                for (int i = 0; i < 4; ++i)
                    acc[i][t] = __builtin_amdgcn_mfma_f32_16x16x32_bf16(a[i][s], buf1[p], acc[i][t], 0, 0, 0);
            }
            store_H(H, j + 1, quad, l16, acc, bt0, bt1);
        }
        wp += 8192;
    }
    // wp = group 8 base; buf0 = group 8
    __syncthreads();   // single wave: compiles to a waitcnt, effectively free

    // ---- layer 2 A-frags from LDS ----
    #pragma unroll
    for (int i = 0; i < 4; ++i)
        #pragma unroll
        for (int s = 0; s < 8; ++s) {
            int row = i * 16 + l16;
            a[i][s] = *(const bf16x8*)(H + row * 256 + (((s * 4 + quad) + row) & 31) * 8);
        }
    __syncthreads();

    // ---- layer 2: groups 8..23 (slab j = even group t0 + odd group t1) ----
    #pragma unroll 1
    for (int j = 0; j < 8; ++j) {
        load_group_p(wp + 4096, lane, buf1);         // odd group of this slab
        float bt0 = b2[j * 32 + l16];
        float bt1 = b2[j * 32 + 16 + l16];
        f32x4 acc[4][2] = {};
        #pragma unroll
        for (int p = 0; p < 8; ++p)
            #pragma unroll
            for (int i = 0; i < 4; ++i)
                acc[i][0] = __builtin_amdgcn_mfma_f32_16x16x32_bf16(a[i][p], buf0[p], acc[i][0], 0, 0, 0);
        load_group_p(wp + 8192, lane, buf0);         // even group of next slab
        #pragma unroll
        for (int p = 0; p < 8; ++p)
            #pragma unroll
            for (int i = 0; i < 4; ++i)
                acc[i][1] = __builtin_amdgcn_mfma_f32_16x16x32_bf16(a[i][p], buf1[p], acc[i][1], 0, 0, 0);
        store_H(H, j, quad, l16, acc, bt0, bt1);
        wp += 8192;
    }
    // wp = group 24 base; buf0 = group 24
    __syncthreads();

    // ---- layer 3 A-frags from LDS ----
    #pragma unroll
    for (int i = 0; i < 4; ++i)
        #pragma unroll
        for (int s = 0; s < 8; ++s) {
            int row = i * 16 + l16;
            a[i][s] = *(const bf16x8*)(H + row * 256 + (((s * 4 + quad) + row) & 31) * 8);
        }

    // ---- layer 3: groups 24..31 (4 slabs), pooled atomic output ----
    #pragma unroll 1
    for (int j = 0; j < 4; ++j) {
        load_group_p(wp + 4096, lane, buf1);
        float bt0 = bo[j * 32 + l16];
        float bt1 = bo[j * 32 + 16 + l16];
        f32x4 acc[4][2] = {};
        #pragma unroll
        for (int p = 0; p < 8; ++p)
            #pragma unroll
            for (int i = 0; i < 4; ++i)
                acc[i][0] = __builtin_amdgcn_mfma_f32_16x16x32_bf16(a[i][p], buf0[p], acc[i][0], 0, 0, 0);
        load_group_p(wp + 8192, lane, buf0);  // last iter reads past Wp into pairBuf (harmless)
        #pragma unroll
        for (int p = 0; p < 8; ++p)
            #pragma unroll
            for (int i = 0; i < 4; ++i)
                acc[i][1] = __builtin_amdgcn_mfma_f32_16x16x32_bf16(a[i][p], buf1[p], acc[i][1], 0, 0, 0);

        if (gfirst == glast) {
            #pragma unroll
            for (int t = 0; t < 2; ++t) {
                float sum = 0.f;
                #pragma unroll
                for (int i = 0; i < 4; ++i)
                    #pragma unroll
                    for (int rr = 0; rr < 4; ++rr) sum += acc[i][t][rr];
                sum += __shfl_xor(sum, 16, 64);
                sum += __shfl_xor(sum, 32, 64);
                if (quad == 0) {
                    int c = j * 32 + t * 16 + l16;
                    float bb = t ? bt1 : bt0;
                    atomicAdd(out + (size_t)gfirst * OUT_DIM + c, sum + 64.f * bb);
                }
            }
        } else {
            #pragma unroll
            for (int i = 0; i < 4; ++i)
                #pragma unroll
                for (int rr = 0; rr < 4; ++rr) {
                    int m = r0g + i * 16 + quad * 4 + rr;
                    if (m < N_NODES) {
                        int g = batch[m];
                        #pragma unroll
                        for (int t = 0; t < 2; ++t) {
                            int c = j * 32 + t * 16 + l16;
                            float bb = t ? bt1 : bt0;
                            atomicAdd(out + (size_t)g * OUT_DIM + c, acc[i][t][rr] + bb);
                        }
                    }
                }
        }
        wp += 8192;
    }
}

extern "C" void kernel_launch(void* const* d_in, const int* in_sizes, int n_in,
                              void* d_out, int out_size, void* d_ws, size_t ws_size,
                              hipStream_t stream) {
    const float* x  = (const float*)d_in[0];
    const int*   ei = (const int*)d_in[1];
    const int*   bi = (const int*)d_in[2];
    const float* W1 = (const float*)d_in[3];
    const float* b1 = (const float*)d_in[4];
    const float* W2 = (const float*)d_in[5];
    const float* b2 = (const float*)d_in[6];
    const float* Wo = (const float*)d_in[7];
    const float* bo = (const float*)d_in[8];
    float* out = (float*)d_out;

    __bf16* A  = (__bf16*)d_ws;                        // [M_PAD][128]
    __bf16* xb = A + (size_t)M_PAD * IN_DIM;           // [N_NODES][128]
    __bf16* Wp = xb + (size_t)N_NODES * IN_DIM;        // [131072] packed frag-ordered
    unsigned* pairBuf = (unsigned*)(Wp + WP_TOTAL);    // [NB*BCAP]
    int* nbr      = (int*)(pairBuf + (size_t)NB * BCAP);
    int* offsets  = nbr + (size_t)NB * BCAP;
    int* deg      = offsets + N_NODES;
    int* gcursor  = deg + N_NODES;

    // ---- fused init ----
    init_kernel<<<(R_TOTAL + 255) / 256, 256, 0, stream>>>(
        x, W1, W2, Wo, xb, A + (size_t)N_NODES * IN_DIM, Wp, out, gcursor);

    // ---- CSR build ----
    bucket_v2_kernel<<<BKB, 256, 0, stream>>>(ei, gcursor, pairBuf);
    passB_kernel<<<NB, 256, 0, stream>>>(pairBuf, gcursor, nbr, offsets, deg);

    // ---- aggregate ----
    aggregate_kernel<<<(N_NODES + 3) / 4, 256, 0, stream>>>(xb, offsets, deg, nbr, A);

    // ---- fused MLP + pool (1-wave blocks, 64 rows/wave, reg dbuf stream) ----
    mlp_fused<<<M_PAD / MLP_ROWS_W, 64, 0, stream>>>(A, Wp, b1, b2, bo, out, bi);
}

// Round 7
// 287.618 us; speedup vs baseline: 1.1673x; 1.1559x over previous
//
#include <hip/hip_runtime.h>

#define N_NODES  100000
#define M_PAD    100096   // 782 * 128 (and 3128 * 32)
#define N_EDGES  1600000
#define N_GRAPHS 512
#define IN_DIM   128
#define HID_DIM  256
#define OUT_DIM  128

#define NB       782      // buckets of 128 nodes
#define BCAP     3072     // mean 2048, +22 sigma headroom
#define CHUNK    2048     // edges per bucket_v2 block
#define BKB      ((N_EDGES + CHUNK - 1) / CHUNK)   // 782

typedef __bf16 bf16x8 __attribute__((ext_vector_type(8)));
typedef __bf16 bf16x4 __attribute__((ext_vector_type(4)));
typedef __bf16 bf16x2 __attribute__((ext_vector_type(2)));
typedef float  f32x4  __attribute__((ext_vector_type(4)));

// ---- packed weight buffer layout (frag-ordered, LINEAR group stream) ----
// 32 groups x 8 frags x 512 elems: L1 groups 0-7, L2 8-23, L3 24-31.
#define WP_L2_BASE 32768
#define WP_L3_BASE 98304
#define WP_TOTAL   131072

// ---------------- fused init ----------------
#define R_X    (N_NODES * IN_DIM / 4)
#define R_APAD ((M_PAD - N_NODES) * IN_DIM / 4)
#define R_WP   WP_TOTAL
#define R_OUT  (N_GRAPHS * OUT_DIM / 4)
#define R_CUR  NB
#define R_TOTAL (R_X + R_APAD + R_WP + R_OUT + R_CUR)

__global__ __launch_bounds__(256) void init_kernel(const float* __restrict__ x,
                                                   const float* __restrict__ W1,
                                                   const float* __restrict__ W2,
                                                   const float* __restrict__ Wo,
                                                   __bf16* __restrict__ xb,
                                                   __bf16* __restrict__ Apad,
                                                   __bf16* __restrict__ Wp,
                                                   float* __restrict__ outbuf,
                                                   int* __restrict__ gcursor) {
    long long i = (long long)blockIdx.x * blockDim.x + threadIdx.x;
    if (i < R_X) {
        float4 v = ((const float4*)x)[i];
        bf16x4 h;
        h.x = (__bf16)v.x; h.y = (__bf16)v.y; h.z = (__bf16)v.z; h.w = (__bf16)v.w;
        ((bf16x4*)xb)[i] = h;
        return;
    }
    i -= R_X;
    if (i < R_APAD) {
        bf16x4 z; z.x = (__bf16)0.f; z.y = (__bf16)0.f; z.z = (__bf16)0.f; z.w = (__bf16)0.f;
        ((bf16x4*)Apad)[i] = z;
        return;
    }
    i -= R_APAD;
    if (i < R_WP) {
        int idx = (int)i;
        const float* src;
        int K, Nn, base;
        if (idx < WP_L2_BASE)      { src = W1; K = 128; Nn = 256; base = 0; }
        else if (idx < WP_L3_BASE) { src = W2; K = 256; Nn = 256; base = WP_L2_BASE; }
        else                       { src = Wo; K = 256; Nn = 128; base = WP_L3_BASE; }
        int r0 = idx - base;
        int slabElems = 32 * K;          // power of two
        int j = r0 / slabElems;
        int r = r0 % slabElems;
        int KS = K / 32;
        int p = r >> 9;
        int lane = (r >> 3) & 63;
        int e = r & 7;
        int s = p % KS, t = p / KS;
        int quad = lane >> 4, l16 = lane & 15;
        int n = j * 32 + t * 16 + l16;
        int k = s * 32 + quad * 8 + e;
        Wp[idx] = (__bf16)src[(size_t)k * Nn + n];
        return;
    }
    i -= R_WP;
    if (i < R_OUT) {
        ((float4*)outbuf)[i] = make_float4(0.f, 0.f, 0.f, 0.f);
        return;
    }
    i -= R_OUT;
    if (i < R_CUR) gcursor[i] = 0;
}

// ---------------- bucket_v2: LDS-staged edge binning ----------------
__global__ __launch_bounds__(256) void bucket_v2_kernel(const int* __restrict__ ei,
                                                        int* __restrict__ gcursor,
                                                        unsigned* __restrict__ pairBuf) {
    __shared__ int lcnt[NB];
    __shared__ int lbase[NB];
    const int tid = threadIdx.x;
    const int e0 = blockIdx.x * CHUNK;

    for (int b = tid; b < NB; b += 256) lcnt[b] = 0;
    __syncthreads();

    for (int i = tid; i < CHUNK; i += 256) {
        int e = e0 + i;
        if (e < N_EDGES) atomicAdd(&lcnt[ei[N_EDGES + e] >> 7], 1);
    }
    __syncthreads();

    for (int b = tid; b < NB; b += 256) {
        int c = lcnt[b];
        lbase[b] = c ? atomicAdd(&gcursor[b], c) : 0;
        lcnt[b] = 0;
    }
    __syncthreads();

    for (int i = tid; i < CHUNK; i += 256) {
        int e = e0 + i;
        if (e < N_EDGES) {
            int s = ei[e];
            int d = ei[N_EDGES + e];
            int b = d >> 7;
            int pos = lbase[b] + atomicAdd(&lcnt[b], 1);
            if (pos < BCAP)
                pairBuf[(size_t)b * BCAP + pos] = (unsigned)s | ((unsigned)(d & 127) << 17);
        }
    }
}

// ---------------- aggB: fused per-bucket CSR build (LDS) + gather aggregate ----------------
// v8: passB + aggregate fused. The per-bucket CSR (<=3072 pairs = 12KB) never
// touches global: phase 1 = count/prefix/scatter into LDS `sorted`; phase 2 =
// aggregate's wave-gather loop reading indices from LDS. Eliminates nbr
// global write (1.6M scattered 4B stores, 64B-line amplified) + nbr re-read
// + offsets/deg traffic + one kernel launch. Gather traffic (410MB random
// 256B rows from L2/L3) is graph-structural and unchanged.
#define AGG_THREADS 512

__global__ __launch_bounds__(AGG_THREADS) void aggB_kernel(const unsigned* __restrict__ pairBuf,
                                                           const int* __restrict__ gcursor,
                                                           const __bf16* __restrict__ xb,
                                                           __bf16* __restrict__ A) {
    __shared__ int lcnt[128];
    __shared__ int loffs[128];
    __shared__ int lcur[128];
    __shared__ int offx[128];
    __shared__ unsigned sorted[BCAP];   // 12 KB

    const int b = blockIdx.x;
    const int tid = threadIdx.x;
    const int node0 = b << 7;
    const int cnt = min(gcursor[b], BCAP);
    const unsigned* pb = pairBuf + (size_t)b * BCAP;

    if (tid < 128) { lcnt[tid] = 0; lcur[tid] = 0; }
    __syncthreads();

    for (int i = tid; i < cnt; i += AGG_THREADS)
        atomicAdd(&lcnt[pb[i] >> 17], 1);
    __syncthreads();

    if (tid < 128) loffs[tid] = lcnt[tid];
    __syncthreads();
    for (int st = 1; st < 128; st <<= 1) {
        int add = (tid < 128 && tid >= st) ? loffs[tid - st] : 0;
        __syncthreads();
        if (tid < 128) loffs[tid] += add;
        __syncthreads();
    }
    if (tid < 128) offx[tid] = loffs[tid] - lcnt[tid];
    __syncthreads();

    for (int i = tid; i < cnt; i += AGG_THREADS) {
        unsigned u = pb[i];
        int dl = u >> 17;
        int slot = atomicAdd(&lcur[dl], 1);
        sorted[offx[dl] + slot] = u & 0x1FFFF;
    }
    __syncthreads();

    // ---- phase 2: 8 waves x 16 nodes, register-accumulated gather ----
    const int wid = tid >> 6;
    const int lane = tid & 63;
    const int c0 = lane * 2;

    #pragma unroll 1
    for (int n = wid; n < 128; n += (AGG_THREADS / 64)) {
        int v = node0 + n;
        if (v >= N_NODES) break;            // wave-uniform; later n only larger
        int off = offx[n];
        int len = lcnt[n];
        bf16x2 self = *(const bf16x2*)(xb + (size_t)v * IN_DIM + c0);
        float ax = (float)self.x, ay = (float)self.y;

        int addr = off + lane;
        if (addr >= cnt) addr = (cnt > 0) ? cnt - 1 : 0;
        int myidx = (int)sorted[addr];

        int lim = len < 64 ? len : 64;
        int j = 0;
        for (; j + 8 <= lim; j += 8) {
            int s0 = __shfl(myidx, j + 0, 64);
            int s1 = __shfl(myidx, j + 1, 64);
            int s2 = __shfl(myidx, j + 2, 64);
            int s3 = __shfl(myidx, j + 3, 64);
            int s4 = __shfl(myidx, j + 4, 64);
            int s5 = __shfl(myidx, j + 5, 64);
            int s6 = __shfl(myidx, j + 6, 64);
            int s7 = __shfl(myidx, j + 7, 64);
            bf16x2 v0 = *(const bf16x2*)(xb + (size_t)s0 * IN_DIM + c0);
            bf16x2 v1 = *(const bf16x2*)(xb + (size_t)s1 * IN_DIM + c0);
            bf16x2 v2 = *(const bf16x2*)(xb + (size_t)s2 * IN_DIM + c0);
            bf16x2 v3 = *(const bf16x2*)(xb + (size_t)s3 * IN_DIM + c0);
            bf16x2 v4 = *(const bf16x2*)(xb + (size_t)s4 * IN_DIM + c0);
            bf16x2 v5 = *(const bf16x2*)(xb + (size_t)s5 * IN_DIM + c0);
            bf16x2 v6 = *(const bf16x2*)(xb + (size_t)s6 * IN_DIM + c0);
            bf16x2 v7 = *(const bf16x2*)(xb + (size_t)s7 * IN_DIM + c0);
            ax += (float)v0.x + (float)v1.x + (float)v2.x + (float)v3.x
                + (float)v4.x + (float)v5.x + (float)v6.x + (float)v7.x;
            ay += (float)v0.y + (float)v1.y + (float)v2.y + (float)v3.y
                + (float)v4.y + (float)v5.y + (float)v6.y + (float)v7.y;
        }
        for (; j < lim; ++j) {
            int s = __shfl(myidx, j, 64);
            bf16x2 vv = *(const bf16x2*)(xb + (size_t)s * IN_DIM + c0);
            ax += (float)vv.x;
            ay += (float)vv.y;
        }
        for (; j < len; ++j) {
            int s = (int)sorted[off + j];
            bf16x2 vv = *(const bf16x2*)(xb + (size_t)s * IN_DIM + c0);
            ax += (float)vv.x;
            ay += (float)vv.y;
        }
        bf16x2 h;
        h.x = (__bf16)ax;
        h.y = (__bf16)ay;
        *(bf16x2*)(A + (size_t)v * IN_DIM + c0) = h;
    }
}

// ---------------- fused 3-layer MLP + pool (v2, 72us proven — FROZEN) ----------------
// Six rounds of variants (LDS weight staging, multi-wave sharing, DMA+drain0,
// DMA+counted-vmcnt, 64-row waves) all lost to this structure; the compiler
// caps live VGPRs (~100-128) and sinks any register prefetch, and every
// block-sync scheme costs more than the ~250cy L2 latency it hides at 16
// MFMA per 8KB group. Do not touch.
__device__ __forceinline__ void load_group_p(const __bf16* __restrict__ p, int lane,
                                             bf16x8* __restrict__ dst) {
    #pragma unroll
    for (int e = 0; e < 8; ++e)
        dst[e] = *(const bf16x8*)(p + (e * 64 + lane) * 8);
}

__device__ __forceinline__ void store_H(__bf16* __restrict__ H, int j, int quad, int l16,
                                        const f32x4 (&acc)[2][2], float bt0, float bt1) {
    const int c7 = l16 & 7;
    const int ch = l16 >> 3;
    #pragma unroll
    for (int i = 0; i < 2; ++i)
        #pragma unroll
        for (int t = 0; t < 2; ++t) {
            const float bb = t ? bt1 : bt0;
            #pragma unroll
            for (int rr = 0; rr < 4; ++rr) {
                int row = i * 16 + quad * 4 + rr;
                int cidx = (j * 4 + t * 2 + ch + row) & 31;
                float v = fmaxf(acc[i][t][rr] + bb, 0.f);
                H[row * 256 + cidx * 8 + c7] = (__bf16)v;
            }
        }
}

__global__ __launch_bounds__(64) void mlp_fused(const __bf16* __restrict__ A,
                                                const __bf16* __restrict__ Wp,
                                                const float* __restrict__ b1,
                                                const float* __restrict__ b2,
                                                const float* __restrict__ bo,
                                                float* __restrict__ out,
                                                const int* __restrict__ batch) {
    __shared__ __bf16 H[32 * 256];   // 16 KB

    const int lane = threadIdx.x;
    const int quad = lane >> 4, l16 = lane & 15;
    const size_t mblk = (size_t)blockIdx.x * 32;
    const int r0g = (int)mblk;
    int gfirst = (r0g < N_NODES) ? batch[r0g] : -2;
    int glast  = (r0g + 31 < N_NODES) ? batch[r0g + 31] : -1;

    bf16x8 a[2][8];
    bf16x8 buf0[8];
    bf16x8 buf1[8];

    const __bf16* wp = Wp;           // group pointer (advances through linear stream)
    load_group_p(wp, lane, buf0);    // prologue: group 0

    // layer-1 A-frags
    #pragma unroll
    for (int i = 0; i < 2; ++i)
        #pragma unroll
        for (int s = 0; s < 4; ++s)
            a[i][s] = *(const bf16x8*)(A + (mblk + i * 16 + l16) * IN_DIM + s * 32 + quad * 8);

    // ---- layer 1: groups 0..7 (unroll-by-2: group parity alternates buf0/buf1) ----
    #pragma unroll 1
    for (int j = 0; j < 8; j += 2) {
        {   // even j: compute buf0, prefetch into buf1
            load_group_p(wp + 4096, lane, buf1);
            float bt0 = b1[j * 32 + l16];
            float bt1 = b1[j * 32 + 16 + l16];
            f32x4 acc[2][2] = {};
            #pragma unroll
            for (int p = 0; p < 8; ++p) {
                const int t = p >> 2, s = p & 3;
                acc[0][t] = __builtin_amdgcn_mfma_f32_16x16x32_bf16(a[0][s], buf0[p], acc[0][t], 0, 0, 0);
                acc[1][t] = __builtin_amdgcn_mfma_f32_16x16x32_bf16(a[1][s], buf0[p], acc[1][t], 0, 0, 0);
            }
            store_H(H, j, quad, l16, acc, bt0, bt1);
        }
        {   // odd j+1: compute buf1, prefetch into buf0
            load_group_p(wp + 8192, lane, buf0);
            float bt0 = b1[(j + 1) * 32 + l16];
            float bt1 = b1[(j + 1) * 32 + 16 + l16];
            f32x4 acc[2][2] = {};
            #pragma unroll
            for (int p = 0; p < 8; ++p) {
                const int t = p >> 2, s = p & 3;
                acc[0][t] = __builtin_amdgcn_mfma_f32_16x16x32_bf16(a[0][s], buf1[p], acc[0][t], 0, 0, 0);
                acc[1][t] = __builtin_amdgcn_mfma_f32_16x16x32_bf16(a[1][s], buf1[p], acc[1][t], 0, 0, 0);
            }
            store_H(H, j + 1, quad, l16, acc, bt0, bt1);
        }
        wp += 8192;
    }
    // wp = group 8 base; buf0 = group 8
    __syncthreads();

    // ---- layer 2 A-frags from LDS ----
    #pragma unroll
    for (int i = 0; i < 2; ++i)
        #pragma unroll
        for (int s = 0; s < 8; ++s) {
            int row = i * 16 + l16;
            a[i][s] = *(const bf16x8*)(H + row * 256 + (((s * 4 + quad) + row) & 31) * 8);
        }
    __syncthreads();

    // ---- layer 2: groups 8..23 (slab j -> even group t=0, odd group t=1) ----
    #pragma unroll 1
    for (int j = 0; j < 8; ++j) {
        load_group_p(wp + 4096, lane, buf1);         // odd group of this slab
        float bt0 = b2[j * 32 + l16];
        float bt1 = b2[j * 32 + 16 + l16];
        f32x4 acc[2][2] = {};
        #pragma unroll
        for (int p = 0; p < 8; ++p) {
            acc[0][0] = __builtin_amdgcn_mfma_f32_16x16x32_bf16(a[0][p], buf0[p], acc[0][0], 0, 0, 0);
            acc[1][0] = __builtin_amdgcn_mfma_f32_16x16x32_bf16(a[1][p], buf0[p], acc[1][0], 0, 0, 0);
        }
        load_group_p(wp + 8192, lane, buf0);         // even group of next slab
        #pragma unroll
        for (int p = 0; p < 8; ++p) {
            acc[0][1] = __builtin_amdgcn_mfma_f32_16x16x32_bf16(a[0][p], buf1[p], acc[0][1], 0, 0, 0);
            acc[1][1] = __builtin_amdgcn_mfma_f32_16x16x32_bf16(a[1][p], buf1[p], acc[1][1], 0, 0, 0);
        }
        store_H(H, j, quad, l16, acc, bt0, bt1);
        wp += 8192;
    }
    // wp = group 24 base; buf0 = group 24
    __syncthreads();

    // ---- layer 3 A-frags from LDS ----
    #pragma unroll
    for (int i = 0; i < 2; ++i)
        #pragma unroll
        for (int s = 0; s < 8; ++s) {
            int row = i * 16 + l16;
            a[i][s] = *(const bf16x8*)(H + row * 256 + (((s * 4 + quad) + row) & 31) * 8);
        }

    // ---- layer 3: groups 24..31 (4 slabs), pooled atomic output ----
    #pragma unroll 1
    for (int j = 0; j < 4; ++j) {
        load_group_p(wp + 4096, lane, buf1);
        float bt0 = bo[j * 32 + l16];
        float bt1 = bo[j * 32 + 16 + l16];
        f32x4 acc[2][2] = {};
        #pragma unroll
        for (int p = 0; p < 8; ++p) {
            acc[0][0] = __builtin_amdgcn_mfma_f32_16x16x32_bf16(a[0][p], buf0[p], acc[0][0], 0, 0, 0);
            acc[1][0] = __builtin_amdgcn_mfma_f32_16x16x32_bf16(a[1][p], buf0[p], acc[1][0], 0, 0, 0);
        }
        load_group_p(wp + 8192, lane, buf0);  // last iter reads past Wp into pairBuf (harmless)
        #pragma unroll
        for (int p = 0; p < 8; ++p) {
            acc[0][1] = __builtin_amdgcn_mfma_f32_16x16x32_bf16(a[0][p], buf1[p], acc[0][1], 0, 0, 0);
            acc[1][1] = __builtin_amdgcn_mfma_f32_16x16x32_bf16(a[1][p], buf1[p], acc[1][1], 0, 0, 0);
        }

        if (gfirst == glast) {
            #pragma unroll
            for (int t = 0; t < 2; ++t) {
                float sum = 0.f;
                #pragma unroll
                for (int i = 0; i < 2; ++i)
                    #pragma unroll
                    for (int rr = 0; rr < 4; ++rr) sum += acc[i][t][rr];
                sum += __shfl_xor(sum, 16, 64);
                sum += __shfl_xor(sum, 32, 64);
                if (quad == 0) {
                    int c = j * 32 + t * 16 + l16;
                    float bb = t ? bt1 : bt0;
                    atomicAdd(out + (size_t)gfirst * OUT_DIM + c, sum + 32.f * bb);
                }
            }
        } else {
            #pragma unroll
            for (int i = 0; i < 2; ++i)
                #pragma unroll
                for (int rr = 0; rr < 4; ++rr) {
                    int m = r0g + i * 16 + quad * 4 + rr;
                    if (m < N_NODES) {
                        int g = batch[m];
                        #pragma unroll
                        for (int t = 0; t < 2; ++t) {
                            int c = j * 32 + t * 16 + l16;
                            float bb = t ? bt1 : bt0;
                            atomicAdd(out + (size_t)g * OUT_DIM + c, acc[i][t][rr] + bb);
                        }
                    }
                }
        }
        wp += 8192;
    }
}

extern "C" void kernel_launch(void* const* d_in, const int* in_sizes, int n_in,
                              void* d_out, int out_size, void* d_ws, size_t ws_size,
                              hipStream_t stream) {
    const float* x  = (const float*)d_in[0];
    const int*   ei = (const int*)d_in[1];
    const int*   bi = (const int*)d_in[2];
    const float* W1 = (const float*)d_in[3];
    const float* b1 = (const float*)d_in[4];
    const float* W2 = (const float*)d_in[5];
    const float* b2 = (const float*)d_in[6];
    const float* Wo = (const float*)d_in[7];
    const float* bo = (const float*)d_in[8];
    float* out = (float*)d_out;

    __bf16* A  = (__bf16*)d_ws;                        // [M_PAD][128]
    __bf16* xb = A + (size_t)M_PAD * IN_DIM;           // [N_NODES][128]
    __bf16* Wp = xb + (size_t)N_NODES * IN_DIM;        // [131072] packed frag-ordered
    unsigned* pairBuf = (unsigned*)(Wp + WP_TOTAL);    // [NB*BCAP]
    int* gcursor  = (int*)(pairBuf + (size_t)NB * BCAP);

    // ---- fused init ----
    init_kernel<<<(R_TOTAL + 255) / 256, 256, 0, stream>>>(
        x, W1, W2, Wo, xb, A + (size_t)N_NODES * IN_DIM, Wp, out, gcursor);

    // ---- edge binning ----
    bucket_v2_kernel<<<BKB, 256, 0, stream>>>(ei, gcursor, pairBuf);

    // ---- fused CSR-in-LDS + gather aggregate ----
    aggB_kernel<<<NB, AGG_THREADS, 0, stream>>>(pairBuf, gcursor, xb, A);

    // ---- fused MLP + pool (v2 frozen) ----
    mlp_fused<<<M_PAD / 32, 64, 0, stream>>>(A, Wp, b1, b2, bo, out, bi);
}

// Round 8
// 278.229 us; speedup vs baseline: 1.2066x; 1.0337x over previous
//
#include <hip/hip_runtime.h>

#define N_NODES  100000
#define M_PAD    100096   // 782 * 128 (and 3128 * 32)
#define N_EDGES  1600000
#define N_GRAPHS 512
#define IN_DIM   128
#define HID_DIM  256
#define OUT_DIM  128

#define NB       782      // buckets of 128 nodes
#define BCAP     3072     // mean 2048, +22 sigma headroom
#define CHUNK    2048     // edges per bucket block
#define BKB      ((N_EDGES + CHUNK - 1) / CHUNK)   // 782

typedef __bf16 bf16x8 __attribute__((ext_vector_type(8)));
typedef __bf16 bf16x4 __attribute__((ext_vector_type(4)));
typedef __bf16 bf16x2 __attribute__((ext_vector_type(2)));
typedef float  f32x4  __attribute__((ext_vector_type(4)));

// ---- packed weight buffer layout (frag-ordered, LINEAR group stream) ----
// 32 groups x 8 frags x 512 elems: L1 groups 0-7, L2 8-23, L3 24-31.
#define WP_L2_BASE 32768
#define WP_L3_BASE 98304
#define WP_TOTAL   131072

// ---- fused init+bucket grid ----
#define R_X    (N_NODES * IN_DIM / 4)
#define R_APAD ((M_PAD - N_NODES) * IN_DIM / 4)
#define R_WP   WP_TOTAL
#define R_OUT  (N_GRAPHS * OUT_DIM / 4)
#define R_TOTAL (R_X + R_APAD + R_WP + R_OUT)          // 3350528
#define NI     ((R_TOTAL + 255) / 256)                 // 13088
#define GRID_IB (BKB + NI)

// ---------------- fused init + edge binning ----------------
// v9: init and bucket_v2 are fully independent (bucket needs only ei +
// memset'd gcursor) -> one launch, bucket blocks FIRST so the scatter phase
// overlaps init's pure-BW streaming instead of serializing after it.
__global__ __launch_bounds__(256) void init_bucket_kernel(const float* __restrict__ x,
                                                          const float* __restrict__ W1,
                                                          const float* __restrict__ W2,
                                                          const float* __restrict__ Wo,
                                                          const int* __restrict__ ei,
                                                          __bf16* __restrict__ xb,
                                                          __bf16* __restrict__ Apad,
                                                          __bf16* __restrict__ Wp,
                                                          float* __restrict__ outbuf,
                                                          int* __restrict__ gcursor,
                                                          unsigned* __restrict__ pairBuf) {
    __shared__ int lcnt[NB];
    __shared__ int lbase[NB];
    const int tid = threadIdx.x;

    if (blockIdx.x < BKB) {
        // ---- bucket path (unchanged logic from bucket_v2) ----
        const int e0 = blockIdx.x * CHUNK;

        for (int b = tid; b < NB; b += 256) lcnt[b] = 0;
        __syncthreads();

        for (int i = tid; i < CHUNK; i += 256) {
            int e = e0 + i;
            if (e < N_EDGES) atomicAdd(&lcnt[ei[N_EDGES + e] >> 7], 1);
        }
        __syncthreads();

        for (int b = tid; b < NB; b += 256) {
            int c = lcnt[b];
            lbase[b] = c ? atomicAdd(&gcursor[b], c) : 0;
            lcnt[b] = 0;
        }
        __syncthreads();

        for (int i = tid; i < CHUNK; i += 256) {
            int e = e0 + i;
            if (e < N_EDGES) {
                int s = ei[e];
                int d = ei[N_EDGES + e];
                int b = d >> 7;
                int pos = lbase[b] + atomicAdd(&lcnt[b], 1);
                if (pos < BCAP)
                    pairBuf[(size_t)b * BCAP + pos] = (unsigned)s | ((unsigned)(d & 127) << 17);
            }
        }
        return;
    }

    // ---- init path (unchanged logic; gcursor zeroing moved to memset) ----
    long long i = (long long)(blockIdx.x - BKB) * blockDim.x + tid;
    if (i < R_X) {
        float4 v = ((const float4*)x)[i];
        bf16x4 h;
        h.x = (__bf16)v.x; h.y = (__bf16)v.y; h.z = (__bf16)v.z; h.w = (__bf16)v.w;
        ((bf16x4*)xb)[i] = h;
        return;
    }
    i -= R_X;
    if (i < R_APAD) {
        bf16x4 z; z.x = (__bf16)0.f; z.y = (__bf16)0.f; z.z = (__bf16)0.f; z.w = (__bf16)0.f;
        ((bf16x4*)Apad)[i] = z;
        return;
    }
    i -= R_APAD;
    if (i < R_WP) {
        int idx = (int)i;
        const float* src;
        int K, Nn, base;
        if (idx < WP_L2_BASE)      { src = W1; K = 128; Nn = 256; base = 0; }
        else if (idx < WP_L3_BASE) { src = W2; K = 256; Nn = 256; base = WP_L2_BASE; }
        else                       { src = Wo; K = 256; Nn = 128; base = WP_L3_BASE; }
        int r0 = idx - base;
        int slabElems = 32 * K;          // power of two
        int j = r0 / slabElems;
        int r = r0 % slabElems;
        int KS = K / 32;
        int p = r >> 9;
        int lane = (r >> 3) & 63;
        int e = r & 7;
        int s = p % KS, t = p / KS;
        int quad = lane >> 4, l16 = lane & 15;
        int n = j * 32 + t * 16 + l16;
        int k = s * 32 + quad * 8 + e;
        Wp[idx] = (__bf16)src[(size_t)k * Nn + n];
        return;
    }
    i -= R_WP;
    if (i < R_OUT) {
        ((float4*)outbuf)[i] = make_float4(0.f, 0.f, 0.f, 0.f);
        return;
    }
}

// ---------------- aggB: fused per-bucket CSR build (LDS) + gather aggregate ----------------
// (byte-identical to R7's passing version)
#define AGG_THREADS 512

__global__ __launch_bounds__(AGG_THREADS) void aggB_kernel(const unsigned* __restrict__ pairBuf,
                                                           const int* __restrict__ gcursor,
                                                           const __bf16* __restrict__ xb,
                                                           __bf16* __restrict__ A) {
    __shared__ int lcnt[128];
    __shared__ int loffs[128];
    __shared__ int lcur[128];
    __shared__ int offx[128];
    __shared__ unsigned sorted[BCAP];   // 12 KB

    const int b = blockIdx.x;
    const int tid = threadIdx.x;
    const int node0 = b << 7;
    const int cnt = min(gcursor[b], BCAP);
    const unsigned* pb = pairBuf + (size_t)b * BCAP;

    if (tid < 128) { lcnt[tid] = 0; lcur[tid] = 0; }
    __syncthreads();

    for (int i = tid; i < cnt; i += AGG_THREADS)
        atomicAdd(&lcnt[pb[i] >> 17], 1);
    __syncthreads();

    if (tid < 128) loffs[tid] = lcnt[tid];
    __syncthreads();
    for (int st = 1; st < 128; st <<= 1) {
        int add = (tid < 128 && tid >= st) ? loffs[tid - st] : 0;
        __syncthreads();
        if (tid < 128) loffs[tid] += add;
        __syncthreads();
    }
    if (tid < 128) offx[tid] = loffs[tid] - lcnt[tid];
    __syncthreads();

    for (int i = tid; i < cnt; i += AGG_THREADS) {
        unsigned u = pb[i];
        int dl = u >> 17;
        int slot = atomicAdd(&lcur[dl], 1);
        sorted[offx[dl] + slot] = u & 0x1FFFF;
    }
    __syncthreads();

    // ---- phase 2: 8 waves x 16 nodes, register-accumulated gather ----
    const int wid = tid >> 6;
    const int lane = tid & 63;
    const int c0 = lane * 2;

    #pragma unroll 1
    for (int n = wid; n < 128; n += (AGG_THREADS / 64)) {
        int v = node0 + n;
        if (v >= N_NODES) break;            // wave-uniform; later n only larger
        int off = offx[n];
        int len = lcnt[n];
        bf16x2 self = *(const bf16x2*)(xb + (size_t)v * IN_DIM + c0);
        float ax = (float)self.x, ay = (float)self.y;

        int addr = off + lane;
        if (addr >= cnt) addr = (cnt > 0) ? cnt - 1 : 0;
        int myidx = (int)sorted[addr];

        int lim = len < 64 ? len : 64;
        int j = 0;
        for (; j + 8 <= lim; j += 8) {
            int s0 = __shfl(myidx, j + 0, 64);
            int s1 = __shfl(myidx, j + 1, 64);
            int s2 = __shfl(myidx, j + 2, 64);
            int s3 = __shfl(myidx, j + 3, 64);
            int s4 = __shfl(myidx, j + 4, 64);
            int s5 = __shfl(myidx, j + 5, 64);
            int s6 = __shfl(myidx, j + 6, 64);
            int s7 = __shfl(myidx, j + 7, 64);
            bf16x2 v0 = *(const bf16x2*)(xb + (size_t)s0 * IN_DIM + c0);
            bf16x2 v1 = *(const bf16x2*)(xb + (size_t)s1 * IN_DIM + c0);
            bf16x2 v2 = *(const bf16x2*)(xb + (size_t)s2 * IN_DIM + c0);
            bf16x2 v3 = *(const bf16x2*)(xb + (size_t)s3 * IN_DIM + c0);
            bf16x2 v4 = *(const bf16x2*)(xb + (size_t)s4 * IN_DIM + c0);
            bf16x2 v5 = *(const bf16x2*)(xb + (size_t)s5 * IN_DIM + c0);
            bf16x2 v6 = *(const bf16x2*)(xb + (size_t)s6 * IN_DIM + c0);
            bf16x2 v7 = *(const bf16x2*)(xb + (size_t)s7 * IN_DIM + c0);
            ax += (float)v0.x + (float)v1.x + (float)v2.x + (float)v3.x
                + (float)v4.x + (float)v5.x + (float)v6.x + (float)v7.x;
            ay += (float)v0.y + (float)v1.y + (float)v2.y + (float)v3.y
                + (float)v4.y + (float)v5.y + (float)v6.y + (float)v7.y;
        }
        for (; j < lim; ++j) {
            int s = __shfl(myidx, j, 64);
            bf16x2 vv = *(const bf16x2*)(xb + (size_t)s * IN_DIM + c0);
            ax += (float)vv.x;
            ay += (float)vv.y;
        }
        for (; j < len; ++j) {
            int s = (int)sorted[off + j];
            bf16x2 vv = *(const bf16x2*)(xb + (size_t)s * IN_DIM + c0);
            ax += (float)vv.x;
            ay += (float)vv.y;
        }
        bf16x2 h;
        h.x = (__bf16)ax;
        h.y = (__bf16)ay;
        *(bf16x2*)(A + (size_t)v * IN_DIM + c0) = h;
    }
}

// ---------------- fused 3-layer MLP + pool (v2, 72us proven — FROZEN) ----------------
// Six rounds of variants (LDS weight staging, multi-wave sharing, DMA+drain0,
// DMA+counted-vmcnt, 64-row waves) all lost to this structure; the compiler
// caps live VGPRs (~100-128) and sinks any register prefetch, and every
// block-sync scheme costs more than the ~250cy L2 latency it hides at 16
// MFMA per 8KB group. Do not touch.
__device__ __forceinline__ void load_group_p(const __bf16* __restrict__ p, int lane,
                                             bf16x8* __restrict__ dst) {
    #pragma unroll
    for (int e = 0; e < 8; ++e)
        dst[e] = *(const bf16x8*)(p + (e * 64 + lane) * 8);
}

__device__ __forceinline__ void store_H(__bf16* __restrict__ H, int j, int quad, int l16,
                                        const f32x4 (&acc)[2][2], float bt0, float bt1) {
    const int c7 = l16 & 7;
    const int ch = l16 >> 3;
    #pragma unroll
    for (int i = 0; i < 2; ++i)
        #pragma unroll
        for (int t = 0; t < 2; ++t) {
            const float bb = t ? bt1 : bt0;
            #pragma unroll
            for (int rr = 0; rr < 4; ++rr) {
                int row = i * 16 + quad * 4 + rr;
                int cidx = (j * 4 + t * 2 + ch + row) & 31;
                float v = fmaxf(acc[i][t][rr] + bb, 0.f);
                H[row * 256 + cidx * 8 + c7] = (__bf16)v;
            }
        }
}

__global__ __launch_bounds__(64) void mlp_fused(const __bf16* __restrict__ A,
                                                const __bf16* __restrict__ Wp,
                                                const float* __restrict__ b1,
                                                const float* __restrict__ b2,
                                                const float* __restrict__ bo,
                                                float* __restrict__ out,
                                                const int* __restrict__ batch) {
    __shared__ __bf16 H[32 * 256];   // 16 KB

    const int lane = threadIdx.x;
    const int quad = lane >> 4, l16 = lane & 15;
    const size_t mblk = (size_t)blockIdx.x * 32;
    const int r0g = (int)mblk;
    int gfirst = (r0g < N_NODES) ? batch[r0g] : -2;
    int glast  = (r0g + 31 < N_NODES) ? batch[r0g + 31] : -1;

    bf16x8 a[2][8];
    bf16x8 buf0[8];
    bf16x8 buf1[8];

    const __bf16* wp = Wp;           // group pointer (advances through linear stream)
    load_group_p(wp, lane, buf0);    // prologue: group 0

    // layer-1 A-frags
    #pragma unroll
    for (int i = 0; i < 2; ++i)
        #pragma unroll
        for (int s = 0; s < 4; ++s)
            a[i][s] = *(const bf16x8*)(A + (mblk + i * 16 + l16) * IN_DIM + s * 32 + quad * 8);

    // ---- layer 1: groups 0..7 (unroll-by-2: group parity alternates buf0/buf1) ----
    #pragma unroll 1
    for (int j = 0; j < 8; j += 2) {
        {   // even j: compute buf0, prefetch into buf1
            load_group_p(wp + 4096, lane, buf1);
            float bt0 = b1[j * 32 + l16];
            float bt1 = b1[j * 32 + 16 + l16];
            f32x4 acc[2][2] = {};
            #pragma unroll
            for (int p = 0; p < 8; ++p) {
                const int t = p >> 2, s = p & 3;
                acc[0][t] = __builtin_amdgcn_mfma_f32_16x16x32_bf16(a[0][s], buf0[p], acc[0][t], 0, 0, 0);
                acc[1][t] = __builtin_amdgcn_mfma_f32_16x16x32_bf16(a[1][s], buf0[p], acc[1][t], 0, 0, 0);
            }
            store_H(H, j, quad, l16, acc, bt0, bt1);
        }
        {   // odd j+1: compute buf1, prefetch into buf0
            load_group_p(wp + 8192, lane, buf0);
            float bt0 = b1[(j + 1) * 32 + l16];
            float bt1 = b1[(j + 1) * 32 + 16 + l16];
            f32x4 acc[2][2] = {};
            #pragma unroll
            for (int p = 0; p < 8; ++p) {
                const int t = p >> 2, s = p & 3;
                acc[0][t] = __builtin_amdgcn_mfma_f32_16x16x32_bf16(a[0][s], buf1[p], acc[0][t], 0, 0, 0);
                acc[1][t] = __builtin_amdgcn_mfma_f32_16x16x32_bf16(a[1][s], buf1[p], acc[1][t], 0, 0, 0);
            }
            store_H(H, j + 1, quad, l16, acc, bt0, bt1);
        }
        wp += 8192;
    }
    // wp = group 8 base; buf0 = group 8
    __syncthreads();

    // ---- layer 2 A-frags from LDS ----
    #pragma unroll
    for (int i = 0; i < 2; ++i)
        #pragma unroll
        for (int s = 0; s < 8; ++s) {
            int row = i * 16 + l16;
            a[i][s] = *(const bf16x8*)(H + row * 256 + (((s * 4 + quad) + row) & 31) * 8);
        }
    __syncthreads();

    // ---- layer 2: groups 8..23 (slab j -> even group t=0, odd group t=1) ----
    #pragma unroll 1
    for (int j = 0; j < 8; ++j) {
        load_group_p(wp + 4096, lane, buf1);         // odd group of this slab
        float bt0 = b2[j * 32 + l16];
        float bt1 = b2[j * 32 + 16 + l16];
        f32x4 acc[2][2] = {};
        #pragma unroll
        for (int p = 0; p < 8; ++p) {
            acc[0][0] = __builtin_amdgcn_mfma_f32_16x16x32_bf16(a[0][p], buf0[p], acc[0][0], 0, 0, 0);
            acc[1][0] = __builtin_amdgcn_mfma_f32_16x16x32_bf16(a[1][p], buf0[p], acc[1][0], 0, 0, 0);
        }
        load_group_p(wp + 8192, lane, buf0);         // even group of next slab
        #pragma unroll
        for (int p = 0; p < 8; ++p) {
            acc[0][1] = __builtin_amdgcn_mfma_f32_16x16x32_bf16(a[0][p], buf1[p], acc[0][1], 0, 0, 0);
            acc[1][1] = __builtin_amdgcn_mfma_f32_16x16x32_bf16(a[1][p], buf1[p], acc[1][1], 0, 0, 0);
        }
        store_H(H, j, quad, l16, acc, bt0, bt1);
        wp += 8192;
    }
    // wp = group 24 base; buf0 = group 24
    __syncthreads();

    // ---- layer 3 A-frags from LDS ----
    #pragma unroll
    for (int i = 0; i < 2; ++i)
        #pragma unroll
        for (int s = 0; s < 8; ++s) {
            int row = i * 16 + l16;
            a[i][s] = *(const bf16x8*)(H + row * 256 + (((s * 4 + quad) + row) & 31) * 8);
        }

    // ---- layer 3: groups 24..31 (4 slabs), pooled atomic output ----
    #pragma unroll 1
    for (int j = 0; j < 4; ++j) {
        load_group_p(wp + 4096, lane, buf1);
        float bt0 = bo[j * 32 + l16];
        float bt1 = bo[j * 32 + 16 + l16];
        f32x4 acc[2][2] = {};
        #pragma unroll
        for (int p = 0; p < 8; ++p) {
            acc[0][0] = __builtin_amdgcn_mfma_f32_16x16x32_bf16(a[0][p], buf0[p], acc[0][0], 0, 0, 0);
            acc[1][0] = __builtin_amdgcn_mfma_f32_16x16x32_bf16(a[1][p], buf0[p], acc[1][0], 0, 0, 0);
        }
        load_group_p(wp + 8192, lane, buf0);  // last iter reads past Wp into pairBuf (harmless)
        #pragma unroll
        for (int p = 0; p < 8; ++p) {
            acc[0][1] = __builtin_amdgcn_mfma_f32_16x16x32_bf16(a[0][p], buf1[p], acc[0][1], 0, 0, 0);
            acc[1][1] = __builtin_amdgcn_mfma_f32_16x16x32_bf16(a[1][p], buf1[p], acc[1][1], 0, 0, 0);
        }

        if (gfirst == glast) {
            #pragma unroll
            for (int t = 0; t < 2; ++t) {
                float sum = 0.f;
                #pragma unroll
                for (int i = 0; i < 2; ++i)
                    #pragma unroll
                    for (int rr = 0; rr < 4; ++rr) sum += acc[i][t][rr];
                sum += __shfl_xor(sum, 16, 64);
                sum += __shfl_xor(sum, 32, 64);
                if (quad == 0) {
                    int c = j * 32 + t * 16 + l16;
                    float bb = t ? bt1 : bt0;
                    atomicAdd(out + (size_t)gfirst * OUT_DIM + c, sum + 32.f * bb);
                }
            }
        } else {
            #pragma unroll
            for (int i = 0; i < 2; ++i)
                #pragma unroll
                for (int rr = 0; rr < 4; ++rr) {
                    int m = r0g + i * 16 + quad * 4 + rr;
                    if (m < N_NODES) {
                        int g = batch[m];
                        #pragma unroll
                        for (int t = 0; t < 2; ++t) {
                            int c = j * 32 + t * 16 + l16;
                            float bb = t ? bt1 : bt0;
                            atomicAdd(out + (size_t)g * OUT_DIM + c, acc[i][t][rr] + bb);
                        }
                    }
                }
        }
        wp += 8192;
    }
}

extern "C" void kernel_launch(void* const* d_in, const int* in_sizes, int n_in,
                              void* d_out, int out_size, void* d_ws, size_t ws_size,
                              hipStream_t stream) {
    const float* x  = (const float*)d_in[0];
    const int*   ei = (const int*)d_in[1];
    const int*   bi = (const int*)d_in[2];
    const float* W1 = (const float*)d_in[3];
    const float* b1 = (const float*)d_in[4];
    const float* W2 = (const float*)d_in[5];
    const float* b2 = (const float*)d_in[6];
    const float* Wo = (const float*)d_in[7];
    const float* bo = (const float*)d_in[8];
    float* out = (float*)d_out;

    __bf16* A  = (__bf16*)d_ws;                        // [M_PAD][128]
    __bf16* xb = A + (size_t)M_PAD * IN_DIM;           // [N_NODES][128]
    __bf16* Wp = xb + (size_t)N_NODES * IN_DIM;        // [131072] packed frag-ordered
    unsigned* pairBuf = (unsigned*)(Wp + WP_TOTAL);    // [NB*BCAP]
    int* gcursor  = (int*)(pairBuf + (size_t)NB * BCAP);

    // ---- zero the per-bucket cursors (decouples bucket blocks from init) ----
    hipMemsetAsync(gcursor, 0, NB * sizeof(int), stream);

    // ---- fused init + edge binning (bucket blocks first) ----
    init_bucket_kernel<<<GRID_IB, 256, 0, stream>>>(
        x, W1, W2, Wo, ei, xb, A + (size_t)N_NODES * IN_DIM, Wp, out, gcursor, pairBuf);

    // ---- fused CSR-in-LDS + gather aggregate ----
    aggB_kernel<<<NB, AGG_THREADS, 0, stream>>>(pairBuf, gcursor, xb, A);

    // ---- fused MLP + pool (v2 frozen) ----
    mlp_fused<<<M_PAD / 32, 64, 0, stream>>>(A, Wp, b1, b2, bo, out, bi);
}